// Round 9
// baseline (1094.725 us; speedup 1.0000x reference)
//
#include <hip/hip_runtime.h>

#define B 32
#define M 4096
#define N 8192
#define DC 10
#define NUM_ITERS 8
#define INV_TEMP 100.0f   // 1/TEMP, TEMP=0.01
#define ALPHA 100.0f
#define NB (N * B)        // 262144
#define MB (M * B)        // 131072
#define NBLK 512
#define TPB 256

// Agent(device)-scope memory ops: bypass the non-coherent per-XCD L2s so the
// persistent kernel's cross-workgroup data flow is correct without per-dispatch
// cache flushes. Costs ~L3 latency, which is what cold-L2 dispatches paid anyway.
__device__ __forceinline__ float agent_load(const float* p) {
    return __hip_atomic_load(p, __ATOMIC_RELAXED, __HIP_MEMORY_SCOPE_AGENT);
}
__device__ __forceinline__ void agent_store(float* p, float v) {
    __hip_atomic_store(p, v, __ATOMIC_RELAXED, __HIP_MEMORY_SCOPE_AGENT);
}

// Sense-reversing grid barrier. cnt returns to 0 after every barrier (and at
// kernel end), gen only advances -> replay-safe; both memset to 0 each call.
// Co-residency: 512 blocks x 256 thr; __launch_bounds__(256,2) caps VGPR at 256
// -> >= 8 waves/CU resident -> all 512 blocks resident (256 CUs x >=2 blocks).
__device__ __forceinline__ void grid_barrier(int* cnt, int* gen) {
    __syncthreads();
    if (threadIdx.x == 0) {
        __threadfence();  // release: drain our stores/atomics to coherence point
        int g = __hip_atomic_load(gen, __ATOMIC_RELAXED, __HIP_MEMORY_SCOPE_AGENT);
        int a = __hip_atomic_fetch_add(cnt, 1, __ATOMIC_ACQ_REL, __HIP_MEMORY_SCOPE_AGENT);
        if (a == NBLK - 1) {
            __hip_atomic_store(cnt, 0, __ATOMIC_RELAXED, __HIP_MEMORY_SCOPE_AGENT);
            __hip_atomic_fetch_add(gen, 1, __ATOMIC_RELEASE, __HIP_MEMORY_SCOPE_AGENT);
        } else {
            while (__hip_atomic_load(gen, __ATOMIC_ACQUIRE, __HIP_MEMORY_SCOPE_AGENT) == g)
                __builtin_amdgcn_s_sleep(1);
        }
    }
    __syncthreads();
}

// Persistent fused BP kernel: whole 8-iteration decode in ONE dispatch.
// Thread (m,b) owns check m/batch b: nbrs, prior[nbrs], syn-sign, and the 10
// c2v messages live in REGISTERS across iterations (never touch memory).
// The same thread also owns var elements (n0,b)=(gid) and (n1,b)=(gid+MB):
// llrs recursion state lp0/lp1 in registers; L in global only for the
// cross-thread check gathers. A single accum buffer is read+rezeroed in the
// var phase each iteration.
__global__ __launch_bounds__(TPB, 2) void bp_kernel(
    const float* __restrict__ syn,    // (B,M)
    const float* __restrict__ prior,  // (N,)
    const float* __restrict__ gamma,  // (N,)
    const int*   __restrict__ nbrs,   // (M,DC)
    float* __restrict__ A,            // (N,B) accum
    float* __restrict__ L,            // (N,B) llrs
    float* __restrict__ out,          // (B,N)
    int*   __restrict__ bar)          // [cnt, gen]
{
    const int gid = blockIdx.x * TPB + threadIdx.x;  // 0..MB-1
    const int b = gid & 31;
    const int m = gid >> 5;

    // ---- one-time per-thread state (registers) ----
    int nb[DC];
    float pnb[DC];
    float c2v[DC];
    const int* nr = nbrs + m * DC;
    #pragma unroll
    for (int i = 0; i < DC; ++i) nb[i] = nr[i];        // broadcast in 32-lane group
    #pragma unroll
    for (int i = 0; i < DC; ++i) pnb[i] = prior[nb[i]];
    const float ssgn = 1.0f - 2.0f * syn[(size_t)b * M + m];

    const int idx0 = gid, idx1 = gid + MB;
    const int n0 = idx0 >> 5, n1 = idx1 >> 5;          // broadcast loads below
    const float p0 = prior[n0], p1 = prior[n1];
    const float g0 = gamma[n0], g1 = gamma[n1];
    const float pg0 = (1.0f - g0) * p0, pg1 = (1.0f - g1) * p1;
    float lp0 = 0.0f, lp1 = 0.0f;                      // llrs_{t-1} (own elements)

    agent_store(&A[idx0], 0.0f);
    agent_store(&A[idx1], 0.0f);

    grid_barrier(bar, bar + 1);

    for (int t = 0; t < NUM_ITERS; ++t) {
        // ================= check phase =================
        float v[DC];
        if (t == 0) {
            #pragma unroll
            for (int i = 0; i < DC; ++i) v[i] = pnb[i];
        } else {
            #pragma unroll
            for (int i = 0; i < DC; ++i)
                v[i] = agent_load(&L[nb[i] * B + b]) - c2v[i];
        }

        float s[DC], a[DC];
        #pragma unroll
        for (int i = 0; i < DC; ++i) {
            a[i] = fabsf(v[i]);
            float tt = __expf(-2.0f * ALPHA * a[i]);       // v_exp_f32
            float mag = (1.0f - tt) / (1.0f + tt);         // tanh(ALPHA*|v|)
            s[i] = copysignf(mag, v[i]);
        }

        // two smallest |v| and argmin
        float min1 = 3.4e38f, min2 = 3.4e38f;
        int am = 0;
        #pragma unroll
        for (int i = 0; i < DC; ++i) {
            if (a[i] < min1) { min2 = min1; min1 = a[i]; am = i; }
            else if (a[i] < min2) { min2 = a[i]; }
        }

        // prefix/suffix sign products for leave-one-out product
        float pre[DC + 1], suf[DC + 1];
        pre[0] = 1.0f;
        #pragma unroll
        for (int i = 0; i < DC; ++i) pre[i + 1] = pre[i] * s[i];
        suf[DC] = 1.0f;
        #pragma unroll
        for (int i = DC - 1; i >= 0; --i) suf[i] = suf[i + 1] * s[i];

        // softmin sums shifted by min1 (w[am] == 1 exactly)
        float w[DC];
        float se = 0.0f, sae = 0.0f;
        #pragma unroll
        for (int i = 0; i < DC; ++i) {
            w[i] = __expf((min1 - a[i]) * INV_TEMP);
            se  += w[i];
            sae += a[i] * w[i];
        }

        // uniform min2-shifted sums for the argmin edge's LOO softmin
        float se2 = 0.0f, sae2 = 0.0f;
        #pragma unroll
        for (int j = 0; j < DC; ++j) {
            float e2 = __expf((min2 - a[j]) * INV_TEMP);
            e2 = (j != am) ? e2 : 0.0f;
            se2  += e2;
            sae2 += a[j] * e2;
        }
        float me_am = sae2 / se2;

        #pragma unroll
        for (int i = 0; i < DC; ++i) {
            float me = (i == am) ? me_am : (sae - a[i] * w[i]) / (se - w[i]);
            float o = ssgn * (pre[i] * suf[i + 1]) * me;
            c2v[i] = o;                                    // stays in registers
            atomicAdd(&A[nb[i] * B + b], o);               // device-scope
        }

        grid_barrier(bar, bar + 1);

        // ================= var phase =================
        float a0 = agent_load(&A[idx0]); agent_store(&A[idx0], 0.0f);
        float a1 = agent_load(&A[idx1]); agent_store(&A[idx1], 0.0f);
        float l0, l1;
        if (t == 0) {
            l0 = a0 + p0;
            l1 = a1 + p1;
        } else {
            l0 = a0 + pg0 + g0 * lp0;
            l1 = a1 + pg1 + g1 * lp1;
        }
        lp0 = l0; lp1 = l1;

        if (t == NUM_ITERS - 1) {
            // final: write transposed output (one-time scattered write)
            out[(size_t)b * N + n0] = l0;
            out[(size_t)b * N + n1] = l1;
        } else {
            agent_store(&L[idx0], l0);
            agent_store(&L[idx1], l1);
            grid_barrier(bar, bar + 1);
        }
    }
}

extern "C" void kernel_launch(void* const* d_in, const int* in_sizes, int n_in,
                              void* d_out, int out_size, void* d_ws, size_t ws_size,
                              hipStream_t stream) {
    const float* syn   = (const float*)d_in[0];   // (B,M)
    const float* prior = (const float*)d_in[1];   // (N,)
    const float* gamma = (const float*)d_in[2];   // (N,)
    const int*   nbrs  = (const int*)d_in[3];     // (M,DC)
    float* out = (float*)d_out;                   // (B,N)

    float* ws = (float*)d_ws;
    float* A  = ws;                               // NB
    float* L  = ws + NB;                          // NB
    int* bar  = (int*)(ws + 2 * (size_t)NB);      // [cnt, gen]

    // barrier state must start at 0 (first call runs on unpoisoned/poisoned ws);
    // the kernel leaves cnt==0 and only advances gen, so this is also replay-safe.
    hipMemsetAsync(bar, 0, 2 * sizeof(int), stream);

    bp_kernel<<<dim3(NBLK), dim3(TPB), 0, stream>>>(syn, prior, gamma, nbrs,
                                                    A, L, out, bar);
}

// Round 10
// 136.863 us; speedup vs baseline: 7.9987x; 7.9987x over previous
//
#include <hip/hip_runtime.h>

#define B 32
#define M 4096
#define N 8192
#define DC 10
#define NUM_ITERS 8
#define INV_TEMP 100.0f   // 1/TEMP, TEMP=0.01
#define ALPHA 100.0f
#define NB (N * B)        // 262144
#define MB (M * B)        // 131072
#define NEDGE (M * DC)    // 40960

// P[k] buffers hold float2 per (n,b): .x = accum (atomic target), .y = llrs
// (owner-written). Rotation at dispatch t: gather P[(t-1)%3] (.x=accum_{t-1},
// .y=llrs_{t-2}), atomics+owner-llrs into P[t%3], zero .x of P[(t+1)%3].

// Prologue 1: init all three P buffers to (0, prior) — .y=prior covers
// degree-0 variables (their llrs_t == prior forever; only deg>=1 entries are
// ever overwritten). Build syn sign (M,B), pg = (1-gamma)*prior, zero
// owner-claim state.
__global__ __launch_bounds__(256) void prologue_kernel(
    const float* __restrict__ syn,    // (B,M)
    const float* __restrict__ prior,  // (N,)
    const float* __restrict__ gamma,  // (N,)
    float2* __restrict__ P0, float2* __restrict__ P1, float2* __restrict__ P2,
    float*  __restrict__ syn_t,       // (M,B)
    float*  __restrict__ pg,          // (N,)
    int*    __restrict__ claim,       // (N,)
    int*    __restrict__ ownbits)     // (M,)
{
    int idx = blockIdx.x * blockDim.x + threadIdx.x;
    if (idx < NB) {
        float2 init = make_float2(0.0f, prior[idx >> 5]);
        P0[idx] = init; P1[idx] = init; P2[idx] = init;
    }
    if (idx < MB) {
        int b = idx & 31, m = idx >> 5;
        syn_t[idx] = 1.0f - 2.0f * syn[(size_t)b * M + m];
    }
    if (idx < N) { pg[idx] = (1.0f - gamma[idx]) * prior[idx]; claim[idx] = 0; }
    if (idx < M) ownbits[idx] = 0;
}

// Prologue 2: claim one owner edge per variable. All candidate writers of a
// variable's llrs compute bit-identical values, so which edge wins is
// output-invisible; ownership only dedups the scattered llrs stores (~5x).
__global__ __launch_bounds__(256) void claim_kernel(
    const int* __restrict__ nbrs,   // (M*DC,)
    int* __restrict__ claim,        // (N,)
    int* __restrict__ ownbits)      // (M,) bit i set => edge (m,i) owns nbrs[m*DC+i]
{
    int e = blockIdx.x * blockDim.x + threadIdx.x;
    if (e >= NEDGE) return;
    if (atomicExch(&claim[nbrs[e]], 1) == 0)
        atomicOr(&ownbits[e / DC], 1 << (e % DC));
}

// Fused check+var kernel (R8 structure + float2 pairing + owner-only stores).
// One thread per (m,b), b innermost (coalesced). Hardware transcendentals
// (validated R8: absmax 0.0625, 6x headroom).
// KIND 0: t=0   v2c = prior[nb]; atomics only.
// KIND 1: t=1   l = Pr.x + prior[nb]   (Pr.y unused); v2c = l - c2v
// KIND 2: t>=2  l = Pr.x + pg + gamma*Pr.y;           v2c = l - c2v
template <int KIND>
__global__ __launch_bounds__(256) void check_kernel(
    const float*  __restrict__ syn_t,  // (M,B) sign form
    const float*  __restrict__ prior,  // (N,)
    const float*  __restrict__ pg,     // (N,)
    const float*  __restrict__ gamma,  // (N,)
    const int*    __restrict__ nbrs,   // (M,DC)
    const int*    __restrict__ ownbits,// (M,)
    const float2* __restrict__ Pr,     // P[(t-1)%3]: (.x=accum_{t-1}, .y=llrs_{t-2})
    float2*       __restrict__ Pw,     // P[t%3]: .x atomic accum_t, .y owner llrs_{t-1}
    float2*       __restrict__ Pz,     // P[(t+1)%3]: zero .x
    float*        __restrict__ c2v)    // (M,DC,B)
{
    int idx = blockIdx.x * blockDim.x + threadIdx.x;  // m*B + b
    if (idx >= MB) return;
    const int b = idx & 31;
    const int m = idx >> 5;

    // zero next iteration's accumulator (.x only; .y holds llrs state)
    Pz[idx].x = 0.0f;
    Pz[idx + MB].x = 0.0f;

    const int* nr = nbrs + m * DC;
    const int ow = ownbits[m];
    float* c2vp = c2v + (size_t)(m * DC) * B + b;

    int nb[DC];
    #pragma unroll
    for (int i = 0; i < DC; ++i) nb[i] = nr[i];   // broadcast across lanes

    float v[DC];
    if (KIND == 0) {
        #pragma unroll
        for (int i = 0; i < DC; ++i) v[i] = prior[nb[i]];
    } else {
        #pragma unroll
        for (int i = 0; i < DC; ++i) {
            const int g = nb[i] * B + b;
            float2 rl = Pr[g];                        // one dwordx2 gather: R + Lold
            float l;
            if (KIND == 1) l = rl.x + prior[nb[i]];
            else           l = rl.x + pg[nb[i]] + gamma[nb[i]] * rl.y;
            if ((ow >> i) & 1) Pw[g].y = l;           // single owner per variable
            v[i] = l - c2vp[(size_t)i * B];
        }
    }

    float s[DC], a[DC];
    #pragma unroll
    for (int i = 0; i < DC; ++i) {
        a[i] = fabsf(v[i]);
        float tt = __expf(-2.0f * ALPHA * a[i]);      // v_exp_f32
        float mag = (1.0f - tt) / (1.0f + tt);        // tanh(ALPHA*|v|)
        s[i] = copysignf(mag, v[i]);
    }

    // two smallest |v| and argmin
    float min1 = 3.4e38f, min2 = 3.4e38f;
    int am = 0;
    #pragma unroll
    for (int i = 0; i < DC; ++i) {
        if (a[i] < min1) { min2 = min1; min1 = a[i]; am = i; }
        else if (a[i] < min2) { min2 = a[i]; }
    }

    // prefix/suffix sign products for leave-one-out product
    float pre[DC + 1], suf[DC + 1];
    pre[0] = 1.0f;
    #pragma unroll
    for (int i = 0; i < DC; ++i) pre[i + 1] = pre[i] * s[i];
    suf[DC] = 1.0f;
    #pragma unroll
    for (int i = DC - 1; i >= 0; --i) suf[i] = suf[i + 1] * s[i];

    // softmin sums shifted by min1 (w[am] == 1 exactly)
    float w[DC];
    float se = 0.0f, sae = 0.0f;
    #pragma unroll
    for (int i = 0; i < DC; ++i) {
        w[i] = __expf((min1 - a[i]) * INV_TEMP);
        se  += w[i];
        sae += a[i] * w[i];
    }

    // uniform (branchless) min2-shifted sums for the argmin edge's LOO softmin
    float se2 = 0.0f, sae2 = 0.0f;
    #pragma unroll
    for (int j = 0; j < DC; ++j) {
        float e2 = __expf((min2 - a[j]) * INV_TEMP);
        e2 = (j != am) ? e2 : 0.0f;
        se2  += e2;
        sae2 += a[j] * e2;
    }
    float me_am = sae2 / se2;

    float ssgn = syn_t[idx];

    #pragma unroll
    for (int i = 0; i < DC; ++i) {
        float me = (i == am) ? me_am : (sae - a[i] * w[i]) / (se - w[i]);
        float out = ssgn * (pre[i] * suf[i + 1]) * me;
        c2vp[(size_t)i * B] = out;
        atomicAdd(&Pw[nb[i] * B + b].x, out);
    }
}

// Epilogue: llrs_7 = accum_7 + pg + gamma*llrs_6 = Pr.x + pg + gamma*Pr.y,
// written transposed to d_out (B,N). Degree-0: .x=0, .y=prior -> correct.
__global__ __launch_bounds__(256) void final_kernel(
    const float2* __restrict__ Pr,   // P[7%3]
    const float*  __restrict__ pg,   // (N,)
    const float*  __restrict__ gamma,// (N,)
    float*        __restrict__ out)  // (B,N)
{
    int idx = blockIdx.x * blockDim.x + threadIdx.x;  // b*N + n (write-coalesced)
    if (idx >= NB) return;
    int n = idx & (N - 1);
    int b = idx >> 13;
    float2 rl = Pr[n * B + b];
    out[idx] = rl.x + pg[n] + gamma[n] * rl.y;
}

extern "C" void kernel_launch(void* const* d_in, const int* in_sizes, int n_in,
                              void* d_out, int out_size, void* d_ws, size_t ws_size,
                              hipStream_t stream) {
    const float* syn   = (const float*)d_in[0];   // (B,M)
    const float* prior = (const float*)d_in[1];   // (N,)
    const float* gamma = (const float*)d_in[2];   // (N,)
    const int*   nbrs  = (const int*)d_in[3];     // (M,DC)
    float* out = (float*)d_out;                   // (B,N)

    char* ws = (char*)d_ws;
    float2* P[3];
    P[0] = (float2*)ws;
    P[1] = P[0] + NB;
    P[2] = P[1] + NB;
    float* c2v    = (float*)(P[2] + NB);          // M*DC*B floats
    float* syn_t  = c2v + (size_t)NEDGE * B;      // MB floats
    float* pg     = syn_t + MB;                   // N floats
    int*   claim  = (int*)(pg + N);               // N ints
    int*   ownbits= claim + N;                    // M ints

    dim3 blk(256);
    dim3 pgrid((NB + 255) / 256);
    dim3 egrid((NEDGE + 255) / 256);
    dim3 cgrid((MB + 255) / 256);

    prologue_kernel<<<pgrid, blk, 0, stream>>>(syn, prior, gamma,
                                               P[0], P[1], P[2], syn_t, pg,
                                               claim, ownbits);
    claim_kernel<<<egrid, blk, 0, stream>>>(nbrs, claim, ownbits);

    for (int t = 0; t < NUM_ITERS; ++t) {
        float2* Pr = P[(t + 2) % 3];   // (t-1) mod 3
        float2* Pw = P[t % 3];
        float2* Pz = P[(t + 1) % 3];
        if (t == 0) {
            check_kernel<0><<<cgrid, blk, 0, stream>>>(syn_t, prior, pg, gamma, nbrs,
                                                       ownbits, Pr, Pw, Pz, c2v);
        } else if (t == 1) {
            check_kernel<1><<<cgrid, blk, 0, stream>>>(syn_t, prior, pg, gamma, nbrs,
                                                       ownbits, Pr, Pw, Pz, c2v);
        } else {
            check_kernel<2><<<cgrid, blk, 0, stream>>>(syn_t, prior, pg, gamma, nbrs,
                                                       ownbits, Pr, Pw, Pz, c2v);
        }
    }
    // final: t=7 wrote atomics into P[1]; llrs_6 owner-written into P[1].y at t=7
    final_kernel<<<pgrid, blk, 0, stream>>>(P[1], pg, gamma, out);
}

// Round 11
// 84.082 us; speedup vs baseline: 13.0197x; 1.6277x over previous
//
#include <hip/hip_runtime.h>

#define B 32
#define M 4096
#define N 8192
#define DC 10
#define NUM_ITERS 8
#define INV_TEMP 100.0f   // 1/TEMP, TEMP=0.01
#define ALPHA 100.0f
#define NB (N * B)        // 262144
#define MB (M * B)        // 131072
#define NEDGE (M * DC)    // 40960

// Prologue: zero accum A0, init L to prior (degree-0 variables: llrs_t == prior
// forever; final_kernel reads L for all n; deg>=1 entries are overwritten at
// t=7), build syn sign (M,B), pg = (1-gamma)*prior.
__global__ __launch_bounds__(256) void prologue_kernel(
    const float* __restrict__ syn,    // (B,M)
    const float* __restrict__ prior,  // (N,)
    const float* __restrict__ gamma,  // (N,)
    float* __restrict__ accumA,       // (N,B)
    float* __restrict__ L,            // (N,B)
    float* __restrict__ syn_t,        // (M,B)
    float* __restrict__ pg)           // (N,)
{
    int idx = blockIdx.x * blockDim.x + threadIdx.x;
    if (idx < NB) {
        accumA[idx] = 0.0f;
        L[idx] = prior[idx >> 5];
    }
    if (idx < MB) {
        int b = idx & 31, m = idx >> 5;
        syn_t[idx] = 1.0f - 2.0f * syn[(size_t)b * M + m];
    }
    if (idx < N) pg[idx] = (1.0f - gamma[idx]) * prior[idx];
}

// Fused check+var kernel, R11: llrs register-recurrence. One thread per (m,b),
// b innermost (coalesced). Persistent per-edge state S[(m*DC+i)*B+b] =
// (.x = c2v_{t-1}[i], .y = llrs_{t-2}[nb_i] replica) — coalesced dwordx2
// streaming, thread-private. Per edge only ONE scattered gather (R) and ONE
// scattered atomic remain; Lold-gathers and redundant Lnew-stores are gone.
// The llrs recursion llrs_{t-1} = R + pg + gamma*llrs_{t-2} is evaluated
// per-thread from the register/state copy — bit-identical to the memory path.
// KIND 0: t=0   v2c = prior[nb]; no S read.
// KIND 1: t=1   l = R + prior[nb]       (S.y unused); v = l - S.x
// KIND 2: t>=2  l = R + pg + gamma*S.y;               v = l - S.x
// WL: write l (= llrs_{t-1}) to L — only at t=7, for final_kernel.
template <int KIND, bool WL>
__global__ __launch_bounds__(256) void check_kernel(
    const float*  __restrict__ syn_t,  // (M,B) sign form
    const float*  __restrict__ prior,  // (N,)
    const float*  __restrict__ pg,     // (N,)
    const float*  __restrict__ gamma,  // (N,)
    const int*    __restrict__ nbrs,   // (M,DC)
    const float*  __restrict__ R,      // accum_{t-1} (N,B)
    float*        __restrict__ W,      // accum_t (N,B), pre-zeroed
    float*        __restrict__ Z,      // accum buffer zeroed here for t+1
    float*        __restrict__ L,      // (N,B), written only when WL
    float2*       __restrict__ S)      // (M,DC,B) per-edge state
{
    int idx = blockIdx.x * blockDim.x + threadIdx.x;  // m*B + b
    if (idx >= MB) return;
    const int b = idx & 31;
    const int m = idx >> 5;

    // zero next iteration's accumulator (2 contiguous elements per thread)
    Z[idx] = 0.0f;
    Z[idx + MB] = 0.0f;

    const int* nr = nbrs + m * DC;
    float2* Sp = S + (size_t)(m * DC) * B + b;

    int nb[DC];
    #pragma unroll
    for (int i = 0; i < DC; ++i) nb[i] = nr[i];   // broadcast across lanes

    float v[DC], lv[DC];
    if (KIND == 0) {
        #pragma unroll
        for (int i = 0; i < DC; ++i) { v[i] = prior[nb[i]]; lv[i] = v[i]; }
    } else {
        #pragma unroll
        for (int i = 0; i < DC; ++i) {
            float2 st = Sp[(size_t)i * B];            // coalesced dwordx2
            const int g = nb[i] * B + b;
            float l;
            if (KIND == 1) l = R[g] + prior[nb[i]];
            else           l = R[g] + pg[nb[i]] + gamma[nb[i]] * st.y;
            if (WL) L[g] = l;                         // only t=7 (llrs_6 for final)
            lv[i] = l;
            v[i] = l - st.x;
        }
    }

    float s[DC], a[DC];
    #pragma unroll
    for (int i = 0; i < DC; ++i) {
        a[i] = fabsf(v[i]);
        float tt = __expf(-2.0f * ALPHA * a[i]);      // v_exp_f32
        float mag = (1.0f - tt) / (1.0f + tt);        // tanh(ALPHA*|v|)
        s[i] = copysignf(mag, v[i]);
    }

    // two smallest |v| and argmin
    float min1 = 3.4e38f, min2 = 3.4e38f;
    int am = 0;
    #pragma unroll
    for (int i = 0; i < DC; ++i) {
        if (a[i] < min1) { min2 = min1; min1 = a[i]; am = i; }
        else if (a[i] < min2) { min2 = a[i]; }
    }

    // prefix/suffix sign products for leave-one-out product
    float pre[DC + 1], suf[DC + 1];
    pre[0] = 1.0f;
    #pragma unroll
    for (int i = 0; i < DC; ++i) pre[i + 1] = pre[i] * s[i];
    suf[DC] = 1.0f;
    #pragma unroll
    for (int i = DC - 1; i >= 0; --i) suf[i] = suf[i + 1] * s[i];

    // softmin sums shifted by min1 (w[am] == 1 exactly)
    float w[DC];
    float se = 0.0f, sae = 0.0f;
    #pragma unroll
    for (int i = 0; i < DC; ++i) {
        w[i] = __expf((min1 - a[i]) * INV_TEMP);
        se  += w[i];
        sae += a[i] * w[i];
    }

    // uniform (branchless) min2-shifted sums for the argmin edge's LOO softmin
    float se2 = 0.0f, sae2 = 0.0f;
    #pragma unroll
    for (int j = 0; j < DC; ++j) {
        float e2 = __expf((min2 - a[j]) * INV_TEMP);
        e2 = (j != am) ? e2 : 0.0f;
        se2  += e2;
        sae2 += a[j] * e2;
    }
    float me_am = sae2 / se2;

    float ssgn = syn_t[idx];

    #pragma unroll
    for (int i = 0; i < DC; ++i) {
        float me = (i == am) ? me_am : (sae - a[i] * w[i]) / (se - w[i]);
        float out = ssgn * (pre[i] * suf[i + 1]) * me;
        Sp[(size_t)i * B] = make_float2(out, lv[i]);  // coalesced dwordx2
        atomicAdd(&W[nb[i] * B + b], out);
    }
}

// Epilogue: llrs_7 = accum_7 + pg + gamma*llrs_6, written transposed to d_out (B,N).
__global__ __launch_bounds__(256) void final_kernel(
    const float* __restrict__ R,     // accum_7 (N,B)
    const float* __restrict__ pg,    // (N,)
    const float* __restrict__ gamma, // (N,)
    const float* __restrict__ L,     // llrs_6 (N,B)
    float*       __restrict__ out)   // (B,N)
{
    int idx = blockIdx.x * blockDim.x + threadIdx.x;  // b*N + n (write-coalesced)
    if (idx >= NB) return;
    int n = idx & (N - 1);
    int b = idx >> 13;
    int goff = n * B + b;
    out[idx] = R[goff] + pg[n] + gamma[n] * L[goff];
}

extern "C" void kernel_launch(void* const* d_in, const int* in_sizes, int n_in,
                              void* d_out, int out_size, void* d_ws, size_t ws_size,
                              hipStream_t stream) {
    const float* syn   = (const float*)d_in[0];   // (B,M)
    const float* prior = (const float*)d_in[1];   // (N,)
    const float* gamma = (const float*)d_in[2];   // (N,)
    const int*   nbrs  = (const int*)d_in[3];     // (M,DC)
    float* out = (float*)d_out;                   // (B,N)

    float* ws = (float*)d_ws;
    float* A[3] = { ws, ws + NB, ws + 2 * (size_t)NB };   // accum rotation
    float* L    = ws + 3 * (size_t)NB;                    // NB (llrs_6 + deg-0 prior)
    float* syn_t= L + NB;                                 // MB
    float* pg   = syn_t + MB;                             // N
    float2* S   = (float2*)(pg + N);                      // NEDGE*B float2

    dim3 blk(256);
    dim3 pgrid((NB + 255) / 256);
    dim3 cgrid((MB + 255) / 256);

    prologue_kernel<<<pgrid, blk, 0, stream>>>(syn, prior, gamma, A[0], L, syn_t, pg);

    for (int t = 0; t < NUM_ITERS; ++t) {
        float* Rb = A[(t + 2) % 3];
        float* Wb = A[t % 3];
        float* Zb = A[(t + 1) % 3];
        if (t == 0) {
            check_kernel<0, false><<<cgrid, blk, 0, stream>>>(syn_t, prior, pg, gamma, nbrs,
                                                              Rb, Wb, Zb, L, S);
        } else if (t == 1) {
            check_kernel<1, false><<<cgrid, blk, 0, stream>>>(syn_t, prior, pg, gamma, nbrs,
                                                              Rb, Wb, Zb, L, S);
        } else if (t < NUM_ITERS - 1) {
            check_kernel<2, false><<<cgrid, blk, 0, stream>>>(syn_t, prior, pg, gamma, nbrs,
                                                              Rb, Wb, Zb, L, S);
        } else {
            // t=7: also materialize llrs_6 into L for the final kernel
            check_kernel<2, true><<<cgrid, blk, 0, stream>>>(syn_t, prior, pg, gamma, nbrs,
                                                             Rb, Wb, Zb, L, S);
        }
    }
    // after t=7: accum_7 = A[7%3] = A[1]; L holds llrs_6 (deg-0: prior)
    final_kernel<<<pgrid, blk, 0, stream>>>(A[1], pg, gamma, L, out);
}

// Round 12
// 79.716 us; speedup vs baseline: 13.7328x; 1.0548x over previous
//
#include <hip/hip_runtime.h>

#define B 32
#define M 4096
#define N 8192
#define DC 10
#define NUM_ITERS 8
#define INV_TEMP 100.0f   // 1/TEMP, TEMP=0.01
#define ALPHA 100.0f
#define NB (N * B)        // 262144
#define MB (M * B)        // 131072
#define NEDGE (M * DC)    // 40960

// Prologue: zero accum A0, init L to prior (degree-0 variables: llrs_t == prior
// forever; final_kernel reads L for all n), build syn sign (M,B),
// pg = (1-gamma)*prior.
__global__ __launch_bounds__(256) void prologue_kernel(
    const float* __restrict__ syn,    // (B,M)
    const float* __restrict__ prior,  // (N,)
    const float* __restrict__ gamma,  // (N,)
    float* __restrict__ accumA,       // (N,B)
    float* __restrict__ L,            // (N,B)
    float* __restrict__ syn_t,        // (M,B)
    float* __restrict__ pg)           // (N,)
{
    int idx = blockIdx.x * blockDim.x + threadIdx.x;
    if (idx < NB) {
        accumA[idx] = 0.0f;
        L[idx] = prior[idx >> 5];
    }
    if (idx < MB) {
        int b = idx & 31, m = idx >> 5;
        syn_t[idx] = 1.0f - 2.0f * syn[(size_t)b * M + m];
    }
    if (idx < N) pg[idx] = (1.0f - gamma[idx]) * prior[idx];
}

// R12: half-split check kernel. One 64-lane wave = one check m:
// lanes 0-31 (h=0) handle edges 0-4 for batches b=0..31,
// lanes 32-63 (h=1) handle edges 5-9. Leave-one-out combine via
// __shfl_xor(...,32) — no LDS, no barrier. Grid 1024 blocks = 16 waves/CU
// (4/SIMD), 2x the R11 occupancy, same total memory traffic, half the
// per-thread VALU. Same min1/min2 select-zero numerics as R11.
// Per-edge persistent state S[(m*DC+i)*B+b] = (.x=c2v_{t-1}, .y=llrs_{t-2} replica).
// KIND 0: t=0   v2c = prior[nb]; no S read.
// KIND 1: t=1   l = R + prior[nb]       (S.y unused); v = l - S.x
// KIND 2: t>=2  l = R + pg + gamma*S.y;               v = l - S.x
// WL: write l (llrs_{t-1}) to L — only t=7, for final_kernel.
template <int KIND, bool WL>
__global__ __launch_bounds__(256, 4) void check_kernel(
    const float*  __restrict__ syn_t,  // (M,B) sign form
    const float*  __restrict__ prior,  // (N,)
    const float*  __restrict__ pg,     // (N,)
    const float*  __restrict__ gamma,  // (N,)
    const int*    __restrict__ nbrs,   // (M,DC)
    const float*  __restrict__ R,      // accum_{t-1} (N,B)
    float*        __restrict__ W,      // accum_t (N,B), pre-zeroed
    float*        __restrict__ Z,      // accum buffer zeroed here for t+1
    float*        __restrict__ L,      // (N,B), written only when WL
    float2*       __restrict__ S)      // (M,DC,B) per-edge state
{
    const int tid  = threadIdx.x;
    const int lane = tid & 63;
    const int b    = lane & 31;
    const int h    = lane >> 5;                    // edge half: 0 -> 0..4, 1 -> 5..9
    const int m    = (blockIdx.x << 2) | (tid >> 6);

    // zero next iteration's accumulator (1 element per thread; grid == NB threads)
    Z[blockIdx.x * 256 + tid] = 0.0f;

    const int* nr = nbrs + m * DC + 5 * h;
    float2* Sp = S + ((size_t)(m * DC + 5 * h)) * B + b;

    int nb[5];
    #pragma unroll
    for (int i = 0; i < 5; ++i) nb[i] = nr[i];     // broadcast within 32-lane group

    float v[5], lv[5];
    if (KIND == 0) {
        #pragma unroll
        for (int i = 0; i < 5; ++i) { v[i] = prior[nb[i]]; lv[i] = v[i]; }
    } else {
        #pragma unroll
        for (int i = 0; i < 5; ++i) {
            float2 st = Sp[(size_t)i * B];          // coalesced dwordx2
            const int g = nb[i] * B + b;
            float l;
            if (KIND == 1) l = R[g] + prior[nb[i]];
            else           l = R[g] + pg[nb[i]] + gamma[nb[i]] * st.y;
            if (WL) L[g] = l;                       // only t=7 (llrs_6 for final)
            lv[i] = l;
            v[i] = l - st.x;
        }
    }

    float s[5], a[5];
    #pragma unroll
    for (int i = 0; i < 5; ++i) {
        a[i] = fabsf(v[i]);
        float tt = __expf(-2.0f * ALPHA * a[i]);    // v_exp_f32
        float mag = (1.0f - tt) / (1.0f + tt);      // tanh(ALPHA*|v|)
        s[i] = copysignf(mag, v[i]);
    }

    // own prefix/suffix sign products; full-product exchange with partner half
    float pre[6], suf[6];
    pre[0] = 1.0f;
    #pragma unroll
    for (int i = 0; i < 5; ++i) pre[i + 1] = pre[i] * s[i];
    suf[5] = 1.0f;
    #pragma unroll
    for (int i = 4; i >= 0; --i) suf[i] = suf[i + 1] * s[i];
    float prod_part = __shfl_xor(pre[5], 32, 64);

    // own two-smallest + argmin (global edge index)
    float m1o = 3.4e38f, m2o = 3.4e38f;
    int amo = 0;
    #pragma unroll
    for (int i = 0; i < 5; ++i) {
        if (a[i] < m1o) { m2o = m1o; m1o = a[i]; amo = i; }
        else if (a[i] < m2o) { m2o = a[i]; }
    }
    int amo_g = amo + 5 * h;

    float m1p   = __shfl_xor(m1o, 32, 64);
    float m2p   = __shfl_xor(m2o, 32, 64);
    int   amp_g = __shfl_xor(amo_g, 32, 64);

    // deterministic h0/h1-ordered merge (both halves compute identical results)
    float m1_0 = h ? m1p : m1o,  m1_1 = h ? m1o : m1p;
    int   am_0 = h ? amp_g : amo_g, am_1 = h ? amo_g : amp_g;
    float min1g = fminf(m1_0, m1_1);
    float min2g = fminf(fmaxf(m1_0, m1_1), fminf(m2o, m2p));
    int   am_g  = (m1_0 <= m1_1) ? am_0 : am_1;

    // min1g-shifted sums (w at the global argmin == 1 exactly)
    float w[5], se = 0.0f, sae = 0.0f;
    #pragma unroll
    for (int i = 0; i < 5; ++i) {
        w[i] = __expf((min1g - a[i]) * INV_TEMP);
        se  += w[i];
        sae += a[i] * w[i];
    }
    float se_tot  = se  + __shfl_xor(se, 32, 64);
    float sae_tot = sae + __shfl_xor(sae, 32, 64);

    // min2g-shifted sums excluding the global argmin (for its LOO softmin)
    float se2 = 0.0f, sae2 = 0.0f;
    #pragma unroll
    for (int i = 0; i < 5; ++i) {
        float e2 = __expf((min2g - a[i]) * INV_TEMP);
        e2 = ((i + 5 * h) != am_g) ? e2 : 0.0f;
        se2  += e2;
        sae2 += a[i] * e2;
    }
    float se2_tot  = se2  + __shfl_xor(se2, 32, 64);
    float sae2_tot = sae2 + __shfl_xor(sae2, 32, 64);
    float me_am = sae2_tot / se2_tot;

    float ssgn = syn_t[(m << 5) | b];

    #pragma unroll
    for (int i = 0; i < 5; ++i) {
        int gi = i + 5 * h;
        float me = (gi == am_g) ? me_am
                                : (sae_tot - a[i] * w[i]) / (se_tot - w[i]);
        float out = ssgn * (pre[i] * suf[i + 1] * prod_part) * me;
        Sp[(size_t)i * B] = make_float2(out, lv[i]);   // coalesced dwordx2
        atomicAdd(&W[nb[i] * B + b], out);
    }
}

// Epilogue: llrs_7 = accum_7 + pg + gamma*llrs_6, written transposed to d_out (B,N).
__global__ __launch_bounds__(256) void final_kernel(
    const float* __restrict__ R,     // accum_7 (N,B)
    const float* __restrict__ pg,    // (N,)
    const float* __restrict__ gamma, // (N,)
    const float* __restrict__ L,     // llrs_6 (N,B)
    float*       __restrict__ out)   // (B,N)
{
    int idx = blockIdx.x * blockDim.x + threadIdx.x;  // b*N + n (write-coalesced)
    if (idx >= NB) return;
    int n = idx & (N - 1);
    int b = idx >> 13;
    int goff = n * B + b;
    out[idx] = R[goff] + pg[n] + gamma[n] * L[goff];
}

extern "C" void kernel_launch(void* const* d_in, const int* in_sizes, int n_in,
                              void* d_out, int out_size, void* d_ws, size_t ws_size,
                              hipStream_t stream) {
    const float* syn   = (const float*)d_in[0];   // (B,M)
    const float* prior = (const float*)d_in[1];   // (N,)
    const float* gamma = (const float*)d_in[2];   // (N,)
    const int*   nbrs  = (const int*)d_in[3];     // (M,DC)
    float* out = (float*)d_out;                   // (B,N)

    float* ws = (float*)d_ws;
    float* A[3] = { ws, ws + NB, ws + 2 * (size_t)NB };   // accum rotation
    float* L    = ws + 3 * (size_t)NB;                    // NB (llrs_6 + deg-0 prior)
    float* syn_t= L + NB;                                 // MB
    float* pg   = syn_t + MB;                             // N
    float2* S   = (float2*)(pg + N);                      // NEDGE*B float2

    dim3 blk(256);
    dim3 pgrid((NB + 255) / 256);
    dim3 cgrid(M / 4);                                    // 1024 blocks, 64 thr/check

    prologue_kernel<<<pgrid, blk, 0, stream>>>(syn, prior, gamma, A[0], L, syn_t, pg);

    for (int t = 0; t < NUM_ITERS; ++t) {
        float* Rb = A[(t + 2) % 3];
        float* Wb = A[t % 3];
        float* Zb = A[(t + 1) % 3];
        if (t == 0) {
            check_kernel<0, false><<<cgrid, blk, 0, stream>>>(syn_t, prior, pg, gamma, nbrs,
                                                              Rb, Wb, Zb, L, S);
        } else if (t == 1) {
            check_kernel<1, false><<<cgrid, blk, 0, stream>>>(syn_t, prior, pg, gamma, nbrs,
                                                              Rb, Wb, Zb, L, S);
        } else if (t < NUM_ITERS - 1) {
            check_kernel<2, false><<<cgrid, blk, 0, stream>>>(syn_t, prior, pg, gamma, nbrs,
                                                              Rb, Wb, Zb, L, S);
        } else {
            check_kernel<2, true><<<cgrid, blk, 0, stream>>>(syn_t, prior, pg, gamma, nbrs,
                                                             Rb, Wb, Zb, L, S);
        }
    }
    // after t=7: accum_7 = A[7%3] = A[1]; L holds llrs_6 (deg-0: prior)
    final_kernel<<<pgrid, blk, 0, stream>>>(A[1], pg, gamma, L, out);
}